// Round 7
// baseline (64.272 us; speedup 1.0000x reference)
//
#include <hip/hip_runtime.h>

#define TOTAL     4194304
#define DIM       32
#define NTOK      (TOTAL / DIM)   // 131072 tokens
#define NCODE     1024
#define CCODES    512             // codes per chunk (2 chunks total)
#define DELTA_EPS 2e-3f
#define FLAGBIT   0x40000000

typedef _Float16 half8   __attribute__((ext_vector_type(8)));
typedef float    floatx4 __attribute__((ext_vector_type(4)));

#define GLOAD_LDS16(g, l) \
    __builtin_amdgcn_global_load_lds((const __attribute__((address_space(1))) void*)(g), \
                                     (__attribute__((address_space(3))) void*)(l), 16, 0, 0)
#define GLOAD_LDS4(g, l) \
    __builtin_amdgcn_global_load_lds((const __attribute__((address_space(1))) void*)(g), \
                                     (__attribute__((address_space(3))) void*)(l), 4, 0, 0)

// ---------------- prep: codebook -> f16 hi/lo split in FRAGMENT ORDER + (-0.5*|e|^2) ----
// Chunk = 512 codes. slot = chunk*2048 + step*64 + l4*16 + l15 (8 halves = 16 B per slot),
// step = (k&511)>>4. Main stages/reads with purely linear lane*16B addressing.
__global__ __launch_bounds__(64) void vq_prep(
    const float* __restrict__ cb, float* __restrict__ nhb,
    _Float16* __restrict__ Eh, _Float16* __restrict__ El)
{
    const int k = blockIdx.x * 64 + threadIdx.x;   // code id
    const float4* e4 = reinterpret_cast<const float4*>(cb) + (size_t)k * 8;
    float v[DIM];
    float4 t[8];
#pragma unroll
    for (int j = 0; j < 8; ++j) t[j] = e4[j];
#pragma unroll
    for (int j = 0; j < 8; ++j) {
        v[4 * j + 0] = t[j].x; v[4 * j + 1] = t[j].y;
        v[4 * j + 2] = t[j].z; v[4 * j + 3] = t[j].w;
    }
    float e2 = 0.0f;
#pragma unroll
    for (int i = 0; i < DIM; ++i) e2 = fmaf(v[i], v[i], e2);   // sequential: matches rescore
    nhb[k] = -0.5f * e2;

    const int chunk = k >> 9, within = k & 511;
    const int step = within >> 4, l15 = within & 15;
#pragma unroll
    for (int l4 = 0; l4 < 4; ++l4) {
        half8 h, lo;
#pragma unroll
        for (int j = 0; j < 8; ++j) {
            float x = v[l4 * 8 + j];
            _Float16 hh = (_Float16)x;
            h[j]  = hh;
            lo[j] = (_Float16)(x - (float)hh);
        }
        const int slot = chunk * 2048 + step * 64 + l4 * 16 + l15;
        *reinterpret_cast<half8*>(Eh + (size_t)slot * 8) = h;
        *reinterpret_cast<half8*>(El + (size_t)slot * 8) = lo;
    }
}

// ---------------- main: MFMA argmax + inline exact rescore of near-ties ----------------
// 512 blocks x 256 tokens; wave owns 64 tokens (m=4 tiles) -> 12 MFMA per ds_read pair.
__global__ __launch_bounds__(256) void vq_main(
    const float* __restrict__ w, const float* __restrict__ c,
    const float* __restrict__ nhb, const _Float16* __restrict__ Eh,
    const _Float16* __restrict__ El, const float* __restrict__ cb,
    int* __restrict__ out)
{
    __shared__ _Float16 sEh[2048 * 8];   // 32 KB: [step(32)][lane(64)][8 halves]
    __shared__ _Float16 sEl[2048 * 8];   // 32 KB
    __shared__ float    snh[CCODES];     // 2 KB
    __shared__ int      sOut[256];       // 1 KB

    const int tid  = threadIdx.x;
    const int lane = tid & 63;
    const int wid  = tid >> 6;
    const int tokw = blockIdx.x * 256 + wid * 64;   // 64 tokens per wave
    const int l15  = lane & 15;
    const int l4   = lane >> 4;

    // A fragments: 4 tiles of 16 tokens. A[row=l15][k=l4*8+j]
    half8 xh[4], xl[4];
#pragma unroll
    for (int m = 0; m < 4; ++m) {
        const int token = tokw + m * 16 + l15;
        const float4* pw = reinterpret_cast<const float4*>(w + (size_t)token * DIM + l4 * 8);
        const float4* pc = reinterpret_cast<const float4*>(c + (size_t)token * DIM + l4 * 8);
        float4 a0 = pw[0], a1 = pw[1], b0 = pc[0], b1 = pc[1];
        float xs[8] = {a0.x - b0.x, a0.y - b0.y, a0.z - b0.z, a0.w - b0.w,
                       a1.x - b1.x, a1.y - b1.y, a1.z - b1.z, a1.w - b1.w};
#pragma unroll
        for (int j = 0; j < 8; ++j) {
            _Float16 h = (_Float16)xs[j];
            xh[m][j] = h;
            xl[m][j] = (_Float16)(xs[j] - (float)h);
        }
    }

    const float NEGINF = __uint_as_float(0xFF800000u);
    float best[16], second[16];
#pragma unroll
    for (int q = 0; q < 16; ++q) { best[q] = NEGINF; second[q] = NEGINF; }

    for (int ch = 0; ch < 2; ++ch) {
        if (ch) __syncthreads();   // all waves done reading chunk 0 before overwrite
        {   // stage 512 codes (64 KB + 2 KB) via async global->LDS, all-linear
            const _Float16* gh = Eh + (size_t)ch * 16384;
            const _Float16* gl = El + (size_t)ch * 16384;
#pragma unroll
            for (int r = 0; r < 8; ++r) {
                const int slot = r * 256 + wid * 64;   // wave-uniform LDS base slot
                GLOAD_LDS16(gh + (size_t)(slot + lane) * 8, sEh + (size_t)slot * 8);
                GLOAD_LDS16(gl + (size_t)(slot + lane) * 8, sEl + (size_t)slot * 8);
            }
#pragma unroll
            for (int r = 0; r < 2; ++r)
                GLOAD_LDS4(nhb + ch * CCODES + wid * 128 + r * 64 + lane,
                           snh + wid * 128 + r * 64);
        }
        __syncthreads();   // drains vmcnt -> staged data visible

        // 32 steps of 16 codes each
#pragma unroll 4
        for (int step = 0; step < 32; ++step) {
            const half8 eh = *reinterpret_cast<const half8*>(sEh + (size_t)(step * 64 + lane) * 8);
            const half8 el = *reinterpret_cast<const half8*>(sEl + (size_t)(step * 64 + lane) * 8);
            const float nh = snh[step * 16 + l15];
            const unsigned ix = 1023u - (unsigned)(ch * CCODES + step * 16 + l15);
            const floatx4 nv = {nh, nh, nh, nh};
#pragma unroll
            for (int m = 0; m < 4; ++m) {
                floatx4 a = __builtin_amdgcn_mfma_f32_16x16x32_f16(xh[m], eh, nv, 0, 0, 0);
                a = __builtin_amdgcn_mfma_f32_16x16x32_f16(xl[m], eh, a, 0, 0, 0);
                a = __builtin_amdgcn_mfma_f32_16x16x32_f16(xh[m], el, a, 0, 0, 0);
#pragma unroll
                for (int r = 0; r < 4; ++r) {
                    const int q = m * 4 + r;
                    float p = __uint_as_float((__float_as_uint(a[r]) & 0xFFFFFC00u) | ix);
                    // second' = middle of {p, best, second};  best' = max(best, p)
                    second[q] = __builtin_amdgcn_fmed3f(p, best[q], second[q]);
                    best[q]   = fmaxf(best[q], p);
                }
            }
        }
    }

    // reduce across the 16 code-lanes (xor over lane bits 0..3)
#pragma unroll
    for (int sh = 1; sh < 16; sh <<= 1) {
#pragma unroll
        for (int q = 0; q < 16; ++q) {
            float bB = __shfl_xor(best[q], sh);
            float sB = __shfl_xor(second[q], sh);
            second[q] = fmaxf(fmaxf(second[q], sB), fminf(best[q], bB));
            best[q]   = fmaxf(best[q], bB);
        }
    }

    // stage per-token results (k | optional FLAGBIT) into wave-local LDS scratch
    if (l15 == 0) {
#pragma unroll
        for (int m = 0; m < 4; ++m) {
#pragma unroll
            for (int r = 0; r < 4; ++r) {
                const int q = m * 4 + r;
                unsigned ub = __float_as_uint(best[q]);
                unsigned us = __float_as_uint(second[q]);
                float bv = __uint_as_float(ub & 0xFFFFFC00u);
                float sv = __uint_as_float(us & 0xFFFFFC00u);
                int eb = (int)((ub >> 23) & 255u);
                int es = (int)((us >> 23) & 255u);
                int em = eb > es ? eb : es;
                em = em > 12 ? em : 12;
                // flag threshold = 4 * packing granule (2^(em-127-12)) + eps
                float thr = __uint_as_float((unsigned)(em - 11) << 23) + DELTA_EPS;
                int k = 1023 - (int)(ub & 1023u);
                sOut[wid * 64 + m * 16 + l4 * 4 + r] = ((bv - sv) < thr) ? (k | FLAGBIT) : k;
            }
        }
    }

    // lane i owns token tokw+i; rescore flagged tokens exactly (wave-cooperative)
    int myval = sOut[wid * 64 + lane];
    unsigned long long mask = __ballot((myval & FLAGBIT) != 0);
    while (mask) {
        const int src = __ffsll(mask) - 1;
        mask &= mask - 1;
        const int token = tokw + src;   // wave-uniform

        float x[DIM];
#pragma unroll
        for (int i = 0; i < DIM; ++i)
            x[i] = w[(size_t)token * DIM + i] - c[(size_t)token * DIM + i];
        float x2 = 0.f;
#pragma unroll
        for (int i = 0; i < DIM; ++i) x2 = fmaf(x[i], x[i], x2);

        float dmin = INFINITY;
        int   kbest = 0;
#pragma unroll 2
        for (int i = 0; i < 16; ++i) {
            const int k = lane + 64 * i;           // ascending per lane
            const float* e = cb + (size_t)k * DIM;
            float dot = 0.f;
#pragma unroll
            for (int j = 0; j < DIM; ++j) dot = fmaf(x[j], e[j], dot);
            float e2 = -2.0f * nhb[k];             // bit-exact |e|^2 (seq-fma in prep)
            float dd = fmaf(-2.0f, dot, x2) + e2;
            if (dd < dmin) { dmin = dd; kbest = k; }
        }
#pragma unroll
        for (int sh = 1; sh < 64; sh <<= 1) {
            float dB = __shfl_xor(dmin, sh);
            int   iB = __shfl_xor(kbest, sh);
            bool take = (dB < dmin) || (dB == dmin && iB < kbest);
            dmin = take ? dB : dmin;
            kbest = take ? iB : kbest;
        }
        if (lane == src) myval = kbest;   // exact index, flag cleared
    }
    out[tokw + lane] = myval;   // coalesced 256 B per wave

}

extern "C" void kernel_launch(void* const* d_in, const int* in_sizes, int n_in,
                              void* d_out, int out_size, void* d_ws, size_t ws_size,
                              hipStream_t stream) {
    const float* w  = (const float*)d_in[0];   // weights   [4194304]
    const float* c  = (const float*)d_in[1];   // condition [1,32,131072] flat
    const float* cb = (const float*)d_in[2];   // codebook  [1024,32]
    int* out = (int*)d_out;                    // int32 indices [131072]

    char* wsb = (char*)d_ws;
    float*    nhb = (float*)wsb;                       // 4 KB
    _Float16* Eh  = (_Float16*)(wsb + 4096);           // 64 KB (fragment-ordered)
    _Float16* El  = (_Float16*)(wsb + 4096 + 65536);   // 64 KB (fragment-ordered)

    vq_prep<<<NCODE / 64, 64, 0, stream>>>(cb, nhb, Eh, El);
    vq_main<<<NTOK / 256, 256, 0, stream>>>(w, c, nhb, Eh, El, cb, out);
}